// Round 19
// baseline (451.494 us; speedup 1.0000x reference)
//
#include <hip/hip_runtime.h>

typedef __attribute__((ext_vector_type(4))) float f32x4;
typedef __attribute__((ext_vector_type(8))) short s16x8;

__device__ __forceinline__ ushort f2bf(float f) {
  union { float f; uint u; } v; v.f = f;
  uint r = v.u + 0x7fffu + ((v.u >> 16) & 1u);
  return (ushort)(r >> 16);
}
__device__ __forceinline__ float bf2f(ushort u) {
  union { uint i; float f; } v; v.i = ((uint)u) << 16; return v.f;
}

__device__ __forceinline__ void glds16(const void* g, void* l) {
  __builtin_amdgcn_global_load_lds(
      (const __attribute__((address_space(1))) uint*)g,
      (__attribute__((address_space(3))) uint*)l, 16, 0, 0);
}

// swizzled index into a [rows][256] bf16 tile (16B-chunk XOR by row&7)
__device__ __forceinline__ int asidx(int row, int col) {
  return row*256 + ((((col>>3) ^ (row & 7)))<<3) + (col&7);
}
// swizzled index into a [rows][32] bf16 scratch tile
__device__ __forceinline__ int scridx(int row, int col) {
  return row*32 + ((((col>>3) ^ ((row>>2)&3)))<<3) + (col&7);
}
// swizzled index into a [32 rows][16 cols] bf16 V^T tile (2 chunks/row)
__device__ __forceinline__ int vtidx(int row, int col) {
  return row*16 + ((((col>>3) ^ (row & 1)))<<3) + (col&7);
}

struct WSrc { const float* p[8]; };

// fp32 [*,256,256] (f-major) -> bf16 WT[n=g][k=f] with the chunk XOR swizzle
// baked in, so a LINEAR global_load_lds stage yields the swizzled LDS layout.
__global__ __launch_bounds__(256) void prep_weights(WSrc s, ushort* wq, ushort* wo) {
  int mm = blockIdx.x >> 6;          // 0..15: axis*4 + {0,1,2:qkv mats, 3:wo}
  int t  = blockIdx.x & 63;
  int a = mm >> 2, sub = mm & 3;
  const float* src = (sub < 3) ? (s.p[a*2] + sub*65536) : s.p[a*2+1];
  ushort*      dst = (sub < 3) ? (wq + (a*3 + sub)*65536) : (wo + a*65536);
  int gt = (t >> 3) * 32, ft = (t & 7) * 32;
  __shared__ float tile[32][33];
  int lx = threadIdx.x & 31, ly = threadIdx.x >> 5;
#pragma unroll
  for (int i = 0; i < 4; i++)
    tile[ly + i*8][lx] = src[(ft + ly + i*8)*256 + gt + lx];
  __syncthreads();
#pragma unroll
  for (int i = 0; i < 4; i++) {
    int n = gt + ly + i*8, col = ft + lx;
    dst[asidx(n, col)] = f2bf(tile[lx][ly + i*8]);
  }
}

// 64-token blocks (1024 of them)
template<int AXIS>
__device__ __forceinline__ int token_index(int blk, int row) {
  if (AXIS == 0) {                       // temporal: 8 seqs/block of len 8
    int seq = blk*8 + (row >> 3);
    int t = row & 7;
    int b = seq >> 12, n = seq & 4095;
    return (b*8 + t)*4096 + n;
  } else {                               // spatial: 4 seqs/block of len 16
    int sid = blk*4 + (row >> 4);
    int bt = sid >> 8, lo = sid & 255, r = row & 15;
    if (AXIS == 1) { int hh = lo >> 4, ww = lo & 15; return bt*4096 + r*256 + hh*16 + ww; }
    if (AXIS == 2) { int dd = lo >> 4, ww = lo & 15; return bt*4096 + dd*256 + r*16 + ww; }
    { int dd = lo >> 4, hh = lo & 15; return bt*4096 + dd*256 + hh*16 + r; }
  }
}

// LDS-write publication fence (raw s_barrier does NOT drain ds ops).
#define PUB_BARRIER() do { \
    __builtin_amdgcn_sched_barrier(0); \
    asm volatile("s_waitcnt lgkmcnt(0)" ::: "memory"); \
    __builtin_amdgcn_sched_barrier(0); \
    __builtin_amdgcn_s_barrier(); \
    __builtin_amdgcn_sched_barrier(0); } while (0)

template<int AXIS>
__global__ __launch_bounds__(256, 4) void axial_pass(
    const float* __restrict__ x0, const ushort* __restrict__ xb,
    const ushort* __restrict__ wqkvT, const float* __restrict__ bqkv,
    const ushort* __restrict__ woT, const float* __restrict__ bo,
    float* __restrict__ out, ushort* __restrict__ x1b) {

  // 40 KB -> 4 blocks/CU (16 waves). ushort layout:
  //   Wb0 [0,8192)  Wb1 [8192,16384)   double-buffered 16 KB weight stages
  //   Scr [16384,20480): 4 packets x 1024:
  //        QVt [0,512): Q [16][32] scridx, later V^T [32][16] vtidx
  //        KP  [512,1024): K, then P (cols 16..31 zeroed), then attn-out xpose
  //   X tile [64][256] stages through Wb0+Wb1 (32KB) pre-loop; epilogue bf16
  //   [64][256] staging aliases the same 32KB post-loop.
  __shared__ ushort smem[20480];
  ushort* Scr = smem + 16384;

  const int tid = threadIdx.x, blk = blockIdx.x;
  const int wv = tid >> 6, lane = tid & 63, llo = lane & 15, lhi = lane >> 4;
  const int rg = wv >> 1, ch = wv & 1;   // row-group (32 rows), n-half (16 cols)
  const f32x4 fzero = {0.f, 0.f, 0.f, 0.f};

  auto issue_stage = [&](int s) {
    const ushort* src = (s < 24) ? (wqkvT + (s % 3)*65536 + (s / 3)*8192)
                                 : (woT + (s - 24)*8192);
    const ushort* g = src + wv*2048 + lane*8;
    ushort* l = smem + (s & 1)*8192 + wv*2048;
#pragma unroll
    for (int i = 0; i < 4; i++) glds16(g + i*512, l + i*512);
  };

  // r12-proven collective order: drain own vmcnt+lgkm BEFORE the barrier,
  // issue the next stage AFTER it.
#define STAGE_SYNC(s) do { \
    __builtin_amdgcn_sched_barrier(0); \
    asm volatile("s_waitcnt vmcnt(0) lgkmcnt(0)" ::: "memory"); \
    __builtin_amdgcn_sched_barrier(0); \
    __builtin_amdgcn_s_barrier(); \
    __builtin_amdgcn_sched_barrier(0); \
    if ((s) + 1 < 32) issue_stage((s) + 1); \
  } while (0)

  // ---- stage X tile [64][256] through Wb0+Wb1 (weights not yet issued) ----
  {
    int row = tid >> 2, q = tid & 3;
    int tok = token_index<AXIS>(blk, row);
    if (AXIS == 0) {
      const float4* s4 = (const float4*)(x0 + (size_t)tok*256 + q*64);
#pragma unroll
      for (int c2 = 0; c2 < 8; c2++) {
        float4 v0 = s4[c2*2], v1 = s4[c2*2 + 1];
        s16x8 o;
        o[0] = (short)f2bf(v0.x); o[1] = (short)f2bf(v0.y);
        o[2] = (short)f2bf(v0.z); o[3] = (short)f2bf(v0.w);
        o[4] = (short)f2bf(v1.x); o[5] = (short)f2bf(v1.y);
        o[6] = (short)f2bf(v1.z); o[7] = (short)f2bf(v1.w);
        *(s16x8*)(smem + asidx(row, (q*8 + c2)*8)) = o;
      }
    } else {
      const s16x8* s8 = (const s16x8*)(xb + (size_t)tok*256 + q*64);
#pragma unroll
      for (int c2 = 0; c2 < 8; c2++)
        *(s16x8*)(smem + asidx(row, (q*8 + c2)*8)) = s8[c2];
    }
  }
  __syncthreads();   // X published (full drain)

  // ---- A-fragments: 2 row-groups (32 rows) per wave, in registers ----
  s16x8 af[2][8];
#pragma unroll
  for (int g = 0; g < 2; g++)
#pragma unroll
    for (int ks = 0; ks < 8; ks++)
      af[g][ks] = *(const s16x8*)(smem + asidx(rg*32 + g*16 + llo, (ks*4 + lhi)*8));
  __syncthreads();   // X fully consumed; buffers free for the weight pipeline

  issue_stage(0);

  // projection: 8 B-reads feed 16 MFMAs (2 independent chains)
  auto proj2 = [&](const ushort* buf, f32x4& c0, f32x4& c1) {
    __builtin_amdgcn_s_setprio(1);
#pragma unroll
    for (int ks = 0; ks < 8; ks++) {
      s16x8 bv = *(const s16x8*)(buf + asidx(ch*16 + llo, (ks*4 + lhi)*8));
      c0 = __builtin_amdgcn_mfma_f32_16x16x32_bf16(af[0][ks], bv, c0, 0, 0, 0);
      c1 = __builtin_amdgcn_mfma_f32_16x16x32_bf16(af[1][ks], bv, c1, 0, 0, 0);
    }
    __builtin_amdgcn_s_setprio(0);
  };

  s16x8 af_o[8];   // per-head attn-out A-fragments (own packet), static-indexed

  // ======= head loop (fully unrolled so af_o[h] stays in registers) =========
#pragma unroll
  for (int h = 0; h < 8; h++) {
    // ---- Q (stage 3h) ----
    STAGE_SYNC(3*h);
    {
      f32x4 c0 = fzero, c1 = fzero;
      proj2(smem + ((3*h) & 1)*8192, c0, c1);
      float bi = bqkv[h*32 + ch*16 + llo];
      ushort* q0 = Scr + (rg*2 + 0)*1024;
      ushort* q1 = Scr + (rg*2 + 1)*1024;
#pragma unroll
      for (int r = 0; r < 4; r++) {
        q0[scridx(lhi*4 + r, ch*16 + llo)] = f2bf(c0[r] + bi);
        q1[scridx(lhi*4 + r, ch*16 + llo)] = f2bf(c1[r] + bi);
      }
    }
    // ---- K (stage 3h+1) ----
    STAGE_SYNC(3*h + 1);
    {
      f32x4 c0 = fzero, c1 = fzero;
      proj2(smem + ((3*h + 1) & 1)*8192, c0, c1);
      float bi = bqkv[256 + h*32 + ch*16 + llo];
      ushort* k0 = Scr + (rg*2 + 0)*1024 + 512;
      ushort* k1 = Scr + (rg*2 + 1)*1024 + 512;
#pragma unroll
      for (int r = 0; r < 4; r++) {
        k0[scridx(lhi*4 + r, ch*16 + llo)] = f2bf(c0[r] + bi);
        k1[scridx(lhi*4 + r, ch*16 + llo)] = f2bf(c1[r] + bi);
      }
    }
    // ---- V (stage 3h+2): QK^T/softmax first (Q,K live), then Vt over Q ----
    STAGE_SYNC(3*h + 2);
    {
      // V projection (weight buffer live this whole segment); results in regs
      f32x4 c0 = fzero, c1 = fzero;
      proj2(smem + ((3*h + 2) & 1)*8192, c0, c1);
      float bi = bqkv[512 + h*32 + ch*16 + llo];

      // ---- attention part 1: wave owns packet wv; Q,K reads own-wave ----
      ushort* S = Scr + wv*1024;
      s16x8 aq = *(const s16x8*)(S + scridx(llo, lhi*8));
      s16x8 bk = *(const s16x8*)(S + 512 + scridx(llo, lhi*8));
      f32x4 sc = __builtin_amdgcn_mfma_f32_16x16x32_bf16(aq, bk, fzero, 0, 0, 0);
#pragma unroll
      for (int r = 0; r < 4; r++) {
        float sv = sc[r] * 0.17677669529663689f;
        if (AXIS == 0) {   // two packed length-8 seqs: block-diagonal mask
          int srow = lhi*4 + r;
          if ((srow >> 3) != (llo >> 3)) sv = -1e30f;
        }
        float mx = sv;
        mx = fmaxf(mx, __shfl_xor(mx, 1));
        mx = fmaxf(mx, __shfl_xor(mx, 2));
        mx = fmaxf(mx, __shfl_xor(mx, 4));
        mx = fmaxf(mx, __shfl_xor(mx, 8));
        float e = __expf(sv - mx);
        float sm = e;
        sm += __shfl_xor(sm, 1);
        sm += __shfl_xor(sm, 2);
        sm += __shfl_xor(sm, 4);
        sm += __shfl_xor(sm, 8);
        // P over K (own wave) + explicit zero of k-cols 16..31: the V^T tile
        // below is only 16 t wide, so PV's k>=16 B-reads alias real rows and
        // MUST be multiplied by zero.
        (S + 512)[scridx(lhi*4 + r, llo)]      = f2bf(e * __builtin_amdgcn_rcpf(sm));
        (S + 512)[scridx(lhi*4 + r, 16 + llo)] = 0;
      }
      // all waves' Q-reads consumed before pair-waves overwrite Q with Vt
      PUB_BARRIER();
      {
        ushort* v0 = Scr + (rg*2 + 0)*1024;    // V^T [32 d][16 t] over Q area
        ushort* v1 = Scr + (rg*2 + 1)*1024;
#pragma unroll
        for (int r = 0; r < 4; r++) {
          v0[vtidx(ch*16 + llo, lhi*4 + r)] = f2bf(c0[r] + bi);
          v1[vtidx(ch*16 + llo, lhi*4 + r)] = f2bf(c1[r] + bi);
        }
      }
      PUB_BARRIER();   // Vt published

      // ---- attention part 2: PV (P k-pad zero x aliased Vt reads = 0) ----
      s16x8 ap  = *(const s16x8*)(S + 512 + scridx(llo, lhi*8));
      s16x8 bv0 = *(const s16x8*)(S + vtidx(llo,      (lhi & 1)*8));
      s16x8 bv1 = *(const s16x8*)(S + vtidx(16 + llo, (lhi & 1)*8));
      f32x4 o0 = __builtin_amdgcn_mfma_f32_16x16x32_bf16(ap, bv0, fzero, 0, 0, 0);
      f32x4 o1 = __builtin_amdgcn_mfma_f32_16x16x32_bf16(ap, bv1, fzero, 0, 0, 0);
      // transpose o through own (dead) P area, harvest A-fragment to regs
#pragma unroll
      for (int r = 0; r < 4; r++) {
        (S + 512)[scridx(lhi*4 + r, llo)]      = f2bf(o0[r]);
        (S + 512)[scridx(lhi*4 + r, 16 + llo)] = f2bf(o1[r]);
      }
      af_o[h] = *(const s16x8*)(S + 512 + scridx(llo, lhi*8));
      // our Vt/P reads drain at the next STAGE_SYNC's lgkm-before-barrier;
      // next head's Q/K stores land only after that barrier -> no race.
    }
  }

  // ====== out-proj: stages 24..31; A = af_o (own packet, 16 rows) ===========
  f32x4 acc[16];
#pragma unroll
  for (int i = 0; i < 16; i++) acc[i] = fzero;
#pragma unroll
  for (int st = 0; st < 8; st++) {
    STAGE_SYNC(24 + st);
    const ushort* buf = smem + ((24 + st) & 1)*8192;
    __builtin_amdgcn_s_setprio(1);
#pragma unroll
    for (int ks = 0; ks < 8; ks++) {
      s16x8 b0 = *(const s16x8*)(buf + asidx(llo,      (ks*4 + lhi)*8));
      s16x8 b1 = *(const s16x8*)(buf + asidx(16 + llo, (ks*4 + lhi)*8));
      acc[st*2]   = __builtin_amdgcn_mfma_f32_16x16x32_bf16(af_o[ks], b0, acc[st*2],   0, 0, 0);
      acc[st*2+1] = __builtin_amdgcn_mfma_f32_16x16x32_bf16(af_o[ks], b1, acc[st*2+1], 0, 0, 0);
    }
    __builtin_amdgcn_s_setprio(0);
  }

  // ==== epilogue: stage acc as bf16 over dead Wb (32KB), full-line RMW ======
  ushort* Fep = smem;          // bf16 [64][256] over Wb0+Wb1 (dead)
  PUB_BARRIER();               // all waves done reading Wb/Scr
#pragma unroll
  for (int st = 0; st < 8; st++) {
#pragma unroll
    for (int j = 0; j < 2; j++) {
#pragma unroll
      for (int r = 0; r < 4; r++) {
        int row = wv*16 + lhi*4 + r;
        Fep[asidx(row, st*32 + j*16 + llo)] = f2bf(acc[st*2 + j][r]);
      }
    }
  }
  PUB_BARRIER();   // staged tile published
  {
    int rbase = tid >> 3, g = tid & 7;
#pragma unroll 1
    for (int step = 0; step < 2; step++) {
      int row = rbase + step*32;
      int tok = token_index<AXIS>(blk, row);
      size_t base = (size_t)tok*256;
#pragma unroll
      for (int i = 0; i < 8; i++) {
        int f = i*32 + g*4;    // 8 lanes x 4 cols = 32 consecutive = 128B line
        const ushort* fp = Fep + asidx(row, f);   // f%8 in {0,4}: within chunk
        float4 b = *(const float4*)&bo[f];
        float4 v = {bf2f(fp[0]) + b.x, bf2f(fp[1]) + b.y,
                    bf2f(fp[2]) + b.z, bf2f(fp[3]) + b.w};
        if (AXIS == 0) {
          float4 x = *(const float4*)&x0[base + f];
          v.x += x.x; v.y += x.y; v.z += x.z; v.w += x.w;
          *(float4*)&out[base + f] = v;             // x1 (fp32)
          ushort4 p; p.x = f2bf(v.x); p.y = f2bf(v.y);
          p.z = f2bf(v.z); p.w = f2bf(v.w);
          *(ushort4*)&x1b[base + f] = p;            // x1 (bf16)
        } else {
          float4 o = *(float4*)&out[base + f];
          o.x += v.x; o.y += v.y; o.z += v.z; o.w += v.w;
          *(float4*)&out[base + f] = o;             // accumulate axis contribution
        }
      }
    }
  }
#undef STAGE_SYNC
}

extern "C" void kernel_launch(void* const* d_in, const int* in_sizes, int n_in,
                              void* d_out, int out_size, void* d_ws, size_t ws_size,
                              hipStream_t stream) {
  const float* x = (const float*)d_in[0];
  ushort* wq  = (ushort*)d_ws;                 // 4*3*65536 bf16
  ushort* wo  = wq + 4*3*65536;                // 4*65536 bf16
  ushort* x1b = wo + 4*65536;                  // 65536*256 bf16
  float* out = (float*)d_out;

  WSrc wsrc;
  wsrc.p[0] = (const float*)d_in[1];  wsrc.p[1] = (const float*)d_in[3];
  wsrc.p[2] = (const float*)d_in[5];  wsrc.p[3] = (const float*)d_in[7];
  wsrc.p[4] = (const float*)d_in[9];  wsrc.p[5] = (const float*)d_in[11];
  wsrc.p[6] = (const float*)d_in[13]; wsrc.p[7] = (const float*)d_in[15];
  prep_weights<<<dim3(1024), dim3(256), 0, stream>>>(wsrc, wq, wo);

  const float* bq_t = (const float*)d_in[2];  const float* bo_t = (const float*)d_in[4];
  const float* bq_d = (const float*)d_in[6];  const float* bo_d = (const float*)d_in[8];
  const float* bq_h = (const float*)d_in[10]; const float* bo_h = (const float*)d_in[12];
  const float* bq_w = (const float*)d_in[14]; const float* bo_w = (const float*)d_in[16];

  axial_pass<0><<<dim3(1024), dim3(256), 0, stream>>>(x, nullptr, wq + 0*3*65536, bq_t, wo + 0*65536, bo_t, out, x1b);
  axial_pass<1><<<dim3(1024), dim3(256), 0, stream>>>(nullptr, x1b, wq + 1*3*65536, bq_d, wo + 1*65536, bo_d, out, nullptr);
  axial_pass<2><<<dim3(1024), dim3(256), 0, stream>>>(nullptr, x1b, wq + 2*3*65536, bq_h, wo + 2*65536, bo_h, out, nullptr);
  axial_pass<3><<<dim3(1024), dim3(256), 0, stream>>>(nullptr, x1b, wq + 3*3*65536, bq_w, wo + 3*65536, bo_w, out, nullptr);
}

// Round 20
// 349.917 us; speedup vs baseline: 1.2903x; 1.2903x over previous
//
#include <hip/hip_runtime.h>

typedef __attribute__((ext_vector_type(4))) float f32x4;
typedef __attribute__((ext_vector_type(8))) short s16x8;

__device__ __forceinline__ ushort f2bf(float f) {
  union { float f; uint u; } v; v.f = f;
  uint r = v.u + 0x7fffu + ((v.u >> 16) & 1u);
  return (ushort)(r >> 16);
}

__device__ __forceinline__ void glds16(const void* g, void* l) {
  __builtin_amdgcn_global_load_lds(
      (const __attribute__((address_space(1))) uint*)g,
      (__attribute__((address_space(3))) uint*)l, 16, 0, 0);
}

// swizzled index into a [rows][256] bf16 tile (16B-chunk XOR by row&7)
__device__ __forceinline__ int asidx(int row, int col) {
  return row*256 + ((((col>>3) ^ (row & 7)))<<3) + (col&7);
}
// swizzled index into a [rows][32] bf16 scratch tile
__device__ __forceinline__ int scridx(int row, int col) {
  return row*32 + ((((col>>3) ^ ((row>>2)&3)))<<3) + (col&7);
}
// epilogue fp32 [64][256] staging: XOR bits 2-4 of f by row&7 (float4-safe)
__device__ __forceinline__ int epidx(int row, int f) {
  return row*256 + (f ^ ((row & 7) << 2));
}

struct WSrc { const float* p[8]; };

// fp32 [*,256,256] (f-major) -> bf16 WT[n=g][k=f] with the chunk XOR swizzle
// baked in, so a LINEAR global_load_lds stage yields the swizzled LDS layout.
__global__ __launch_bounds__(256) void prep_weights(WSrc s, ushort* wq, ushort* wo) {
  int mm = blockIdx.x >> 6;          // 0..15: axis*4 + {0,1,2:qkv mats, 3:wo}
  int t  = blockIdx.x & 63;
  int a = mm >> 2, sub = mm & 3;
  const float* src = (sub < 3) ? (s.p[a*2] + sub*65536) : s.p[a*2+1];
  ushort*      dst = (sub < 3) ? (wq + (a*3 + sub)*65536) : (wo + a*65536);
  int gt = (t >> 3) * 32, ft = (t & 7) * 32;
  __shared__ float tile[32][33];
  int lx = threadIdx.x & 31, ly = threadIdx.x >> 5;
#pragma unroll
  for (int i = 0; i < 4; i++)
    tile[ly + i*8][lx] = src[(ft + ly + i*8)*256 + gt + lx];
  __syncthreads();
#pragma unroll
  for (int i = 0; i < 4; i++) {
    int n = gt + ly + i*8, col = ft + lx;
    dst[asidx(n, col)] = f2bf(tile[lx][ly + i*8]);
  }
}

// 64-token blocks (1024 of them)
template<int AXIS>
__device__ __forceinline__ int token_index(int blk, int row) {
  if (AXIS == 0) {                       // temporal: 8 seqs/block of len 8
    int seq = blk*8 + (row >> 3);
    int t = row & 7;
    int b = seq >> 12, n = seq & 4095;
    return (b*8 + t)*4096 + n;
  } else {                               // spatial: 4 seqs/block of len 16
    int sid = blk*4 + (row >> 4);
    int bt = sid >> 8, lo = sid & 255, r = row & 15;
    if (AXIS == 1) { int hh = lo >> 4, ww = lo & 15; return bt*4096 + r*256 + hh*16 + ww; }
    if (AXIS == 2) { int dd = lo >> 4, ww = lo & 15; return bt*4096 + dd*256 + r*16 + ww; }
    { int dd = lo >> 4, hh = lo & 15; return bt*4096 + dd*256 + hh*16 + r; }
  }
}

// LDS-write publication fence (raw s_barrier does NOT drain ds ops).
// Drains lgkm only; outstanding glds (vmcnt) stay in flight across it.
#define PUB_BARRIER() do { \
    __builtin_amdgcn_sched_barrier(0); \
    asm volatile("s_waitcnt lgkmcnt(0)" ::: "memory"); \
    __builtin_amdgcn_sched_barrier(0); \
    __builtin_amdgcn_s_barrier(); \
    __builtin_amdgcn_sched_barrier(0); } while (0)

template<int AXIS>
__global__ __launch_bounds__(256, 2) void axial_pass(
    const float* __restrict__ x0, const ushort* __restrict__ xb,
    const ushort* __restrict__ wqkvT, const float* __restrict__ bqkv,
    const ushort* __restrict__ woT, const float* __restrict__ bo,
    float* __restrict__ out, ushort* __restrict__ x1b) {

  // 64 KB -> 2 blocks/CU. ushort layout:
  //   Wb: 3 x 8192 at 0 / 8192 / 16384  (triple-buffered 16 KB weight stages)
  //   Scr [24576,32768): 4 packets x 2048: Q [0,512) KP [512,1024) Vt [1024,2048)
  //   X tile [64][256] stages through [0,16384) pre-loop (bufs 0,1; issued after).
  //   Epilogue: Fep fp32[64][256] = 64KB aliases the whole smem (all dead).
  __shared__ ushort smem[32768];
  ushort* Scr = smem + 24576;

  const int tid = threadIdx.x, blk = blockIdx.x;
  const int wv = tid >> 6, lane = tid & 63, llo = lane & 15, lhi = lane >> 4;
  const int rg = wv >> 1, ch = wv & 1;   // row-group (32 rows), n-half (16 cols)
  const f32x4 fzero = {0.f, 0.f, 0.f, 0.f};
  const s16x8 szero = {0,0,0,0,0,0,0,0};

  auto issue_stage = [&](int s) {
    const ushort* src = (s < 24) ? (wqkvT + (s % 3)*65536 + (s / 3)*8192)
                                 : (woT + (s - 24)*8192);
    const ushort* g = src + wv*2048 + lane*8;
    ushort* l = smem + (s % 3)*8192 + wv*2048;
#pragma unroll
    for (int i = 0; i < 4; i++) glds16(g + i*512, l + i*512);
  };

  // Collective 2-deep pipelined sync: every wave issues stages in IDENTICAL
  // order, so vmcnt(4) before the barrier drains each wave's own stage-s
  // loads (FIFO; only s+1's 4 remain in flight). Barrier then publishes all
  // waves' deposits. Stage s+2's buffer was last read at compute s-1,
  // finished by all waves before this barrier -> WAR-safe. The awaited stage
  // was issued TWO segments ago, so the wait is ~free.
#define STAGE_SYNC(s) do { \
    __builtin_amdgcn_sched_barrier(0); \
    if ((s) < 31) { asm volatile("s_waitcnt vmcnt(4) lgkmcnt(0)" ::: "memory"); } \
    else          { asm volatile("s_waitcnt vmcnt(0) lgkmcnt(0)" ::: "memory"); } \
    __builtin_amdgcn_sched_barrier(0); \
    __builtin_amdgcn_s_barrier(); \
    __builtin_amdgcn_sched_barrier(0); \
    if ((s) + 2 < 32) issue_stage((s) + 2); \
  } while (0)

  // ---- stage X tile [64][256] through bufs 0+1 (weights not yet issued) ----
  {
    int row = tid >> 2, q = tid & 3;
    int tok = token_index<AXIS>(blk, row);
    if (AXIS == 0) {
      const float4* s4 = (const float4*)(x0 + (size_t)tok*256 + q*64);
#pragma unroll
      for (int c2 = 0; c2 < 8; c2++) {
        float4 v0 = s4[c2*2], v1 = s4[c2*2 + 1];
        s16x8 o;
        o[0] = (short)f2bf(v0.x); o[1] = (short)f2bf(v0.y);
        o[2] = (short)f2bf(v0.z); o[3] = (short)f2bf(v0.w);
        o[4] = (short)f2bf(v1.x); o[5] = (short)f2bf(v1.y);
        o[6] = (short)f2bf(v1.z); o[7] = (short)f2bf(v1.w);
        *(s16x8*)(smem + asidx(row, (q*8 + c2)*8)) = o;
      }
    } else {
      const s16x8* s8 = (const s16x8*)(xb + (size_t)tok*256 + q*64);
#pragma unroll
      for (int c2 = 0; c2 < 8; c2++)
        *(s16x8*)(smem + asidx(row, (q*8 + c2)*8)) = s8[c2];
    }
  }
  // zero own packet's Vt k-pad (cols 16..31) once; read only by this wave
  {
    ushort* Vtw = Scr + wv*2048 + 1024;
    *(s16x8*)(Vtw + scridx(lane >> 1, 16 + (lane & 1)*8)) = szero;
  }
  __syncthreads();   // X + pad published (full drain)

  // ---- A-fragments: 2 row-groups (32 rows) per wave, in registers ----
  s16x8 af[2][8];
#pragma unroll
  for (int g = 0; g < 2; g++)
#pragma unroll
    for (int ks = 0; ks < 8; ks++)
      af[g][ks] = *(const s16x8*)(smem + asidx(rg*32 + g*16 + llo, (ks*4 + lhi)*8));
  __syncthreads();   // X fully consumed; buffers free for the weight pipeline

  issue_stage(0);
  issue_stage(1);

  // projection: 8 B-reads feed 16 MFMAs (2 independent chains)
  auto proj2 = [&](const ushort* buf, f32x4& c0, f32x4& c1) {
    __builtin_amdgcn_s_setprio(1);
#pragma unroll
    for (int ks = 0; ks < 8; ks++) {
      s16x8 bv = *(const s16x8*)(buf + asidx(ch*16 + llo, (ks*4 + lhi)*8));
      c0 = __builtin_amdgcn_mfma_f32_16x16x32_bf16(af[0][ks], bv, c0, 0, 0, 0);
      c1 = __builtin_amdgcn_mfma_f32_16x16x32_bf16(af[1][ks], bv, c1, 0, 0, 0);
    }
    __builtin_amdgcn_s_setprio(0);
  };

  s16x8 af_o[8];   // per-head attn-out A-fragments (own packet), static-indexed

  // ======= head loop (fully unrolled so af_o[h] stays in registers) =========
#pragma unroll
  for (int h = 0; h < 8; h++) {
    // ---- Q (stage 3h) ----
    STAGE_SYNC(3*h);
    {
      f32x4 c0 = fzero, c1 = fzero;
      proj2(smem + ((3*h) % 3)*8192, c0, c1);
      float bi = bqkv[h*32 + ch*16 + llo];
      ushort* q0 = Scr + (rg*2 + 0)*2048;
      ushort* q1 = Scr + (rg*2 + 1)*2048;
#pragma unroll
      for (int r = 0; r < 4; r++) {
        q0[scridx(lhi*4 + r, ch*16 + llo)] = f2bf(c0[r] + bi);
        q1[scridx(lhi*4 + r, ch*16 + llo)] = f2bf(c1[r] + bi);
      }
    }
    // ---- K (stage 3h+1) ----
    STAGE_SYNC(3*h + 1);
    {
      f32x4 c0 = fzero, c1 = fzero;
      proj2(smem + ((3*h + 1) % 3)*8192, c0, c1);
      float bi = bqkv[256 + h*32 + ch*16 + llo];
      ushort* k0 = Scr + (rg*2 + 0)*2048 + 512;
      ushort* k1 = Scr + (rg*2 + 1)*2048 + 512;
#pragma unroll
      for (int r = 0; r < 4; r++) {
        k0[scridx(lhi*4 + r, ch*16 + llo)] = f2bf(c0[r] + bi);
        k1[scridx(lhi*4 + r, ch*16 + llo)] = f2bf(c1[r] + bi);
      }
    }
    // ---- V (stage 3h+2), stored transposed [d][t]; then attention ----
    STAGE_SYNC(3*h + 2);
    {
      f32x4 c0 = fzero, c1 = fzero;
      proj2(smem + ((3*h + 2) % 3)*8192, c0, c1);
      float bi = bqkv[512 + h*32 + ch*16 + llo];
      ushort* v0 = Scr + (rg*2 + 0)*2048 + 1024;
      ushort* v1 = Scr + (rg*2 + 1)*2048 + 1024;
#pragma unroll
      for (int r = 0; r < 4; r++) {
        v0[scridx(ch*16 + llo, lhi*4 + r)] = f2bf(c0[r] + bi);
        v1[scridx(ch*16 + llo, lhi*4 + r)] = f2bf(c1[r] + bi);
      }
      PUB_BARRIER();   // Q,K,V for all packets published (lgkm only)

      // ---- attention: wave owns packet wv; all LDS below same-wave ----
      ushort* S = Scr + wv*2048;
      s16x8 aq = *(const s16x8*)(S + scridx(llo, lhi*8));
      s16x8 bk = *(const s16x8*)(S + 512 + scridx(llo, lhi*8));
      f32x4 sc = __builtin_amdgcn_mfma_f32_16x16x32_bf16(aq, bk, fzero, 0, 0, 0);
#pragma unroll
      for (int r = 0; r < 4; r++) {
        float sv = sc[r] * 0.17677669529663689f;
        if (AXIS == 0) {   // two packed length-8 seqs: block-diagonal mask
          int srow = lhi*4 + r;
          if ((srow >> 3) != (llo >> 3)) sv = -1e30f;
        }
        float mx = sv;
        mx = fmaxf(mx, __shfl_xor(mx, 1));
        mx = fmaxf(mx, __shfl_xor(mx, 2));
        mx = fmaxf(mx, __shfl_xor(mx, 4));
        mx = fmaxf(mx, __shfl_xor(mx, 8));
        float e = __expf(sv - mx);
        float sm = e;
        sm += __shfl_xor(sm, 1);
        sm += __shfl_xor(sm, 2);
        sm += __shfl_xor(sm, 4);
        sm += __shfl_xor(sm, 8);
        (S + 512)[scridx(lhi*4 + r, llo)] = f2bf(e * __builtin_amdgcn_rcpf(sm)); // P over K
      }
      // PV (P k-pad garbage x Vt zero-pad = 0); same-wave in-order LDS
      s16x8 ap  = *(const s16x8*)(S + 512 + scridx(llo, lhi*8));
      s16x8 bv0 = *(const s16x8*)(S + 1024 + scridx(llo, lhi*8));
      s16x8 bv1 = *(const s16x8*)(S + 1024 + scridx(16 + llo, lhi*8));
      f32x4 o0 = __builtin_amdgcn_mfma_f32_16x16x32_bf16(ap, bv0, fzero, 0, 0, 0);
      f32x4 o1 = __builtin_amdgcn_mfma_f32_16x16x32_bf16(ap, bv1, fzero, 0, 0, 0);
      // transpose o through own (dead) Q area, harvest A-fragment to regs
#pragma unroll
      for (int r = 0; r < 4; r++) {
        S[scridx(lhi*4 + r, llo)]      = f2bf(o0[r]);
        S[scridx(lhi*4 + r, 16 + llo)] = f2bf(o1[r]);
      }
      af_o[h] = *(const s16x8*)(S + scridx(llo, lhi*8));
      // attention reads drain at the next STAGE_SYNC's lgkm-before-barrier;
      // next head's Q/K/V stores land only after that barrier -> no race.
    }
  }

  // ====== out-proj: stages 24..31; A = af_o (own packet, 16 rows) ===========
  f32x4 acc[16];
#pragma unroll
  for (int i = 0; i < 16; i++) acc[i] = fzero;
#pragma unroll
  for (int st = 0; st < 8; st++) {
    STAGE_SYNC(24 + st);
    const ushort* buf = smem + ((24 + st) % 3)*8192;
    __builtin_amdgcn_s_setprio(1);
#pragma unroll
    for (int ks = 0; ks < 8; ks++) {
      s16x8 b0 = *(const s16x8*)(buf + asidx(llo,      (ks*4 + lhi)*8));
      s16x8 b1 = *(const s16x8*)(buf + asidx(16 + llo, (ks*4 + lhi)*8));
      acc[st*2]   = __builtin_amdgcn_mfma_f32_16x16x32_bf16(af_o[ks], b0, acc[st*2],   0, 0, 0);
      acc[st*2+1] = __builtin_amdgcn_mfma_f32_16x16x32_bf16(af_o[ks], b1, acc[st*2+1], 0, 0, 0);
    }
    __builtin_amdgcn_s_setprio(0);
  }

  // ======== vectorized epilogue: fp32 staging, full-line RMW ================
  float* Fep = (float*)smem;   // fp32 [64][256] = 64KB over all of smem (dead)
  PUB_BARRIER();               // all waves done reading bufs/Scr
#pragma unroll
  for (int st = 0; st < 8; st++) {
#pragma unroll
    for (int j = 0; j < 2; j++) {
#pragma unroll
      for (int r = 0; r < 4; r++) {
        int row = wv*16 + lhi*4 + r;
        Fep[epidx(row, st*32 + j*16 + llo)] = acc[st*2 + j][r];
      }
    }
  }
  PUB_BARRIER();   // acc tile published
  {
    int rbase = tid >> 3, g = tid & 7;
#pragma unroll 1
    for (int step = 0; step < 2; step++) {
      int row = rbase + step*32;
      int tok = token_index<AXIS>(blk, row);
      size_t base = (size_t)tok*256;
#pragma unroll
      for (int i = 0; i < 8; i++) {
        int f = i*32 + g*4;
        float4 v = *(float4*)&Fep[epidx(row, f)];
        float4 b = *(const float4*)&bo[f];
        v.x += b.x; v.y += b.y; v.z += b.z; v.w += b.w;
        if (AXIS == 0) {
          float4 x = *(const float4*)&x0[base + f];
          v.x += x.x; v.y += x.y; v.z += x.z; v.w += x.w;
          *(float4*)&out[base + f] = v;             // x1 (fp32)
          ushort4 p; p.x = f2bf(v.x); p.y = f2bf(v.y);
          p.z = f2bf(v.z); p.w = f2bf(v.w);
          *(ushort4*)&x1b[base + f] = p;            // x1 (bf16)
        } else {
          float4 o = *(float4*)&out[base + f];
          o.x += v.x; o.y += v.y; o.z += v.z; o.w += v.w;
          *(float4*)&out[base + f] = o;             // accumulate axis contribution
        }
      }
    }
  }
#undef STAGE_SYNC
}

extern "C" void kernel_launch(void* const* d_in, const int* in_sizes, int n_in,
                              void* d_out, int out_size, void* d_ws, size_t ws_size,
                              hipStream_t stream) {
  const float* x = (const float*)d_in[0];
  ushort* wq  = (ushort*)d_ws;                 // 4*3*65536 bf16
  ushort* wo  = wq + 4*3*65536;                // 4*65536 bf16
  ushort* x1b = wo + 4*65536;                  // 65536*256 bf16
  float* out = (float*)d_out;

  WSrc wsrc;
  wsrc.p[0] = (const float*)d_in[1];  wsrc.p[1] = (const float*)d_in[3];
  wsrc.p[2] = (const float*)d_in[5];  wsrc.p[3] = (const float*)d_in[7];
  wsrc.p[4] = (const float*)d_in[9];  wsrc.p[5] = (const float*)d_in[11];
  wsrc.p[6] = (const float*)d_in[13]; wsrc.p[7] = (const float*)d_in[15];
  prep_weights<<<dim3(1024), dim3(256), 0, stream>>>(wsrc, wq, wo);

  const float* bq_t = (const float*)d_in[2];  const float* bo_t = (const float*)d_in[4];
  const float* bq_d = (const float*)d_in[6];  const float* bo_d = (const float*)d_in[8];
  const float* bq_h = (const float*)d_in[10]; const float* bo_h = (const float*)d_in[12];
  const float* bq_w = (const float*)d_in[14]; const float* bo_w = (const float*)d_in[16];

  axial_pass<0><<<dim3(1024), dim3(256), 0, stream>>>(x, nullptr, wq + 0*3*65536, bq_t, wo + 0*65536, bo_t, out, x1b);
  axial_pass<1><<<dim3(1024), dim3(256), 0, stream>>>(nullptr, x1b, wq + 1*3*65536, bq_d, wo + 1*65536, bo_d, out, nullptr);
  axial_pass<2><<<dim3(1024), dim3(256), 0, stream>>>(nullptr, x1b, wq + 2*3*65536, bq_h, wo + 2*65536, bo_h, out, nullptr);
  axial_pass<3><<<dim3(1024), dim3(256), 0, stream>>>(nullptr, x1b, wq + 3*3*65536, bq_w, wo + 3*65536, bo_w, out, nullptr);
}